// Round 4
// baseline (228.077 us; speedup 1.0000x reference)
//
#include <hip/hip_runtime.h>

#define B_    8
#define CIN   128
#define COUT  128
#define NX    8192
#define KMJ   32
#define MODES 256

typedef short bf16x8 __attribute__((ext_vector_type(8)));
typedef float f32x4  __attribute__((ext_vector_type(4)));

__device__ __forceinline__ float bf2f(unsigned short u) {
    union { unsigned int i; float f; } v; v.i = ((unsigned int)u) << 16; return v.f;
}
__device__ __forceinline__ unsigned short f2bf(float f) {
    union { float f; unsigned int i; } v; v.f = f;
    unsigned int x = v.i;
    return (unsigned short)((x + 0x7fffu + ((x >> 16) & 1u)) >> 16);
}
__device__ __forceinline__ bf16x8 cvt8(const float* __restrict__ p) {
    f32x4 a = *(const f32x4*)p;
    f32x4 b = *(const f32x4*)(p + 4);
    bf16x8 r;
    r[0] = (short)f2bf(a[0]); r[1] = (short)f2bf(a[1]);
    r[2] = (short)f2bf(a[2]); r[3] = (short)f2bf(a[3]);
    r[4] = (short)f2bf(b[0]); r[5] = (short)f2bf(b[1]);
    r[6] = (short)f2bf(b[2]); r[7] = (short)f2bf(b[3]);
    return r;
}
__device__ __forceinline__ ushort4 cvt4(f32x4 a) {
    ushort4 r;
    r.x = f2bf(a[0]); r.y = f2bf(a[1]); r.z = f2bf(a[2]); r.w = f2bf(a[3]);
    return r;
}

// ---------------------------------------------------------------------------
// K1 v3: Wk[k][o][i] = sum_j D[j][k] * weights[i][o][j]   (unchanged)
// ---------------------------------------------------------------------------
__global__ __launch_bounds__(256) void k1_wk(const float* __restrict__ W,
                                             const float* __restrict__ D,
                                             unsigned short* __restrict__ Wk) {
    int wave = threadIdx.x >> 6, lane = threadIdx.x & 63;
    int quad = lane >> 4, l16 = lane & 15;
    int gw  = blockIdx.x * 4 + wave;
    int oi0 = gw * 16;
    int i0  = oi0 & 127, o0 = oi0 >> 7;
    bf16x8 bfrag = cvt8(W + ((size_t)(i0 + l16) * COUT + o0) * KMJ + quad * 8);
#pragma unroll
    for (int m = 0; m < 4; m++) {
        int k0 = (blockIdx.y * 4 + m) * 16;
        bf16x8 afrag;
#pragma unroll
        for (int jj = 0; jj < 8; jj++)
            afrag[jj] = (short)f2bf(D[(quad * 8 + jj) * MODES + k0 + l16]);
        f32x4 acc = {0.f, 0.f, 0.f, 0.f};
        acc = __builtin_amdgcn_mfma_f32_16x16x32_bf16(afrag, bfrag, acc, 0, 0, 0);
#pragma unroll
        for (int r = 0; r < 4; r++)
            Wk[(size_t)(k0 + quad * 4 + r) * (CIN * COUT) + oi0 + l16] = f2bf(acc[r]);
    }
}

// ---------------------------------------------------------------------------
// K2 v7: PART[b][np][c][k] = sum_{n in 512-chunk np} x[b][c][n]*wb[b][n][k]
//
// Round-3 post-mortem: occupancy 16->33->67% and burst depth 4->8 all gave
// ZERO movement; per-CU rate saturates ~4.7 B/cyc at >=16 waves. Remaining
// lever is BYTES: v7 halves the partial tensor (16 partials of 512 n, was
// 32x256) -> PART 16.7 -> 8.4 MB bf16, halving the dead write+read
// round-trip. fp32 accumulation now spans 512 n (fewer bf16 roundings ->
// accuracy same or better; n-chunk order unchanged).
// Grid (16,8,2) = 256 blocks x 16 waves = 16 waves/CU (measured saturation).
// ---------------------------------------------------------------------------
__global__ __launch_bounds__(1024, 4) void k2_xhat(const float* __restrict__ X,
                                                   const float* __restrict__ WB,
                                                   unsigned short* __restrict__ PART) {
    __shared__ __align__(16) unsigned short Xs[128 * 40];    // [c][32n], 80B rows
    __shared__ __align__(16) unsigned short WBT[128 * 40];   // [k][32n], 80B rows
    int np = blockIdx.x, b = blockIdx.y, kh = blockIdx.z;
    int r0 = np * 512;
    int t  = threadIdx.x;
    int wave = t >> 6, lane = t & 63;
    int wm = wave >> 2, wk = wave & 3;     // 16 waves: 4x4 over 128c x 128k
    int quad = lane >> 4, l16 = lane & 15;
    int sw = quad ^ (l16 & 3);             // slot swizzle for frag reads

    const float* xb  = X  + (size_t)b * CIN * NX;
    const float* wbb = WB + (size_t)b * NX * MODES + kh * 128;

    bool isX = (t >= 512);                 // waves 8..15 stage X, 0..7 stage WB
    int j  = t & 511;
    int xr = j >> 2, xseg = j & 3;         // X: row xr, cols xseg*8..+7
    int kq = j >> 4, nq = j & 15;          // WB: cols 4kq..+3, rows 2nq,2nq+1

    const float* gx = xb + (size_t)xr * NX + r0 + xseg * 8;
    const float* gw = wbb + (size_t)(r0 + 2 * nq) * MODES + 4 * kq;
    unsigned short* xw = Xs + xr * 40 + ((xseg ^ (xr & 3)) << 3);

    f32x4 acc[2][2];
#pragma unroll
    for (int i = 0; i < 2; i++)
#pragma unroll
        for (int jj = 0; jj < 2; jj++) acc[i][jj] = (f32x4){0.f, 0.f, 0.f, 0.f};

    f32x4 st0, st1;
    if (isX) { st0 = *(const f32x4*)gx; st1 = *(const f32x4*)(gx + 4); }
    else     { st0 = *(const f32x4*)gw; st1 = *(const f32x4*)(gw + MODES); }

    for (int p = 0; p < 16; p++) {
        if (p) __syncthreads();            // prev pass frag reads complete
        if (isX) {
            *(ushort4*)xw       = cvt4(st0);
            *(ushort4*)(xw + 4) = cvt4(st1);
        } else {
#pragma unroll
            for (int jj = 0; jj < 4; jj++) {
                int k = 4 * kq + jj;
                unsigned int w = (unsigned int)f2bf(st0[jj]) |
                                 ((unsigned int)f2bf(st1[jj]) << 16);
                *(unsigned int*)(WBT + k * 40 + (((nq >> 2) ^ (k & 3)) << 3) + ((nq & 3) << 1)) = w;
            }
        }
        __syncthreads();                   // staging visible

        if (p < 15) {                      // issue next pass; drains over MFMA
            if (isX) { gx += 32;          st0 = *(const f32x4*)gx; st1 = *(const f32x4*)(gx + 4); }
            else     { gw += 32 * MODES;  st0 = *(const f32x4*)gw; st1 = *(const f32x4*)(gw + MODES); }
        }

        bf16x8 af[2], bfv[2];
#pragma unroll
        for (int tm = 0; tm < 2; tm++)
            af[tm] = *(const bf16x8*)(Xs + (wm * 32 + tm * 16 + l16) * 40 + (sw << 3));
#pragma unroll
        for (int tn = 0; tn < 2; tn++)
            bfv[tn] = *(const bf16x8*)(WBT + (wk * 32 + tn * 16 + l16) * 40 + (sw << 3));
#pragma unroll
        for (int tm = 0; tm < 2; tm++)
#pragma unroll
            for (int tn = 0; tn < 2; tn++)
                acc[tm][tn] = __builtin_amdgcn_mfma_f32_16x16x32_bf16(af[tm], bfv[tn], acc[tm][tn], 0, 0, 0);
    }

    unsigned short* pb = PART + ((size_t)b * 16 + np) * (CIN * MODES) + kh * 128;
#pragma unroll
    for (int tm = 0; tm < 2; tm++) {
        int c = wm * 32 + tm * 16 + quad * 4;
#pragma unroll
        for (int tn = 0; tn < 2; tn++) {
            int km = wk * 32 + tn * 16 + l16;
#pragma unroll
            for (int r = 0; r < 4; r++)
                pb[(size_t)(c + r) * MODES + km] = f2bf(acc[tm][tn][r]);
        }
    }
}

// ---------------------------------------------------------------------------
// K2b v3: transposing reducer.  XHT[k][b][i] = sum_np PART[b][np][i][k]
// 16-B contiguous PART reads (8 k per thread); LDS transpose; coalesced
// f32x4 row writes.  k3's gather then becomes coalesced row reads.
// np order ascending = same global n order as before.
// ---------------------------------------------------------------------------
__global__ __launch_bounds__(256) void k2b_red(const unsigned short* __restrict__ PART,
                                               float* __restrict__ XHT) {
    __shared__ float xt[8][512];
    int k0 = blockIdx.x * 8, bh = blockIdx.y;
    int t = threadIdx.x;
#pragma unroll
    for (int q = 0; q < 2; q++) {
        int bi = bh * 512 + q * 256 + t;   // b = bi>>7, i = bi&127
        float a[8] = {0.f, 0.f, 0.f, 0.f, 0.f, 0.f, 0.f, 0.f};
        const unsigned short* p = PART + ((size_t)((bi >> 7) * 16) * 128 + (bi & 127)) * MODES + k0;
#pragma unroll
        for (int np = 0; np < 16; np++) {
            bf16x8 v = *(const bf16x8*)p;
#pragma unroll
            for (int jj = 0; jj < 8; jj++) a[jj] += bf2f((unsigned short)v[jj]);
            p += (size_t)128 * MODES;
        }
#pragma unroll
        for (int jj = 0; jj < 8; jj++) xt[jj][q * 256 + t] = a[jj];
    }
    __syncthreads();
#pragma unroll
    for (int q = 0; q < 4; q++) {
        int idx = q * 1024 + t * 4;
        int row = idx >> 9, col = idx & 511;
        *(f32x4*)(XHT + (size_t)(k0 + row) * 1024 + bh * 512 + col) = *(const f32x4*)&xt[row][col];
    }
}

// ---------------------------------------------------------------------------
// K3 v4: y_hat[b][o][k] = sum_i x_hat[b][i][k] * Wk[k][o][i]
// xs fill now COALESCED from XHT[k][b][i] (was 1024 scalar stride-1KB loads).
// Same per-output ii,jj order -> same YH values.
// ---------------------------------------------------------------------------
__global__ __launch_bounds__(256, 2) void k3_yhat(const float* __restrict__ XHT,
                                                  const unsigned short* __restrict__ Wk,
                                                  unsigned short* __restrict__ YH) {
    __shared__ float xs[128][8];
    int k = blockIdx.x, oh = blockIdx.y;
    int t = threadIdx.x;
#pragma unroll
    for (int l = 0; l < 4; l++) {
        int e = l * 256 + t;                   // e = b*128 + i, coalesced
        xs[e & 127][e >> 7] = XHT[(size_t)k * 1024 + e];
    }
    int o = oh * 64 + (t & 63), bq = t >> 6;   // bq 0..3 -> b = 2bq, 2bq+1
    const unsigned short* wp = Wk + (size_t)k * (CIN * COUT) + (size_t)o * CIN;
    bf16x8 wc[16];
#pragma unroll
    for (int ii = 0; ii < 16; ii++)
        wc[ii] = *(const bf16x8*)(wp + ii * 8); // burst 16x16B
    __syncthreads();
    float a0 = 0.f, a1 = 0.f;
#pragma unroll
    for (int ii = 0; ii < 16; ii++)
#pragma unroll
        for (int jj = 0; jj < 8; jj++) {
            float w = bf2f((unsigned short)wc[ii][jj]);
            int i = ii * 8 + jj;
            a0 += w * xs[i][bq * 2];
            a1 += w * xs[i][bq * 2 + 1];
        }
    YH[((size_t)(bq * 2)     * COUT + o) * MODES + k] = f2bf(a0);
    YH[((size_t)(bq * 2 + 1) * COUT + o) * MODES + k] = f2bf(a1);
}

// ---------------------------------------------------------------------------
// K4 v4: y[b][c][n] = sum_k y_hat[b][c][k] * bases[b][n][k]   (unchanged)
// ---------------------------------------------------------------------------
__global__ __launch_bounds__(1024, 8) void k4_y(const unsigned short* __restrict__ YH,
                                                const float* __restrict__ BA,
                                                float* __restrict__ Y) {
    __shared__ __align__(16) unsigned short As[128 * 40];   // [c][32k]
    __shared__ __align__(16) unsigned short Bs[128 * 40];   // [n][32k]
    int b  = blockIdx.y;
    int n0 = blockIdx.x * 128;
    int t  = threadIdx.x;
    int wave = t >> 6, lane = t & 63;
    int wm = wave >> 2, wn = wave & 3;
    int quad = lane >> 4, l16 = lane & 15;
    int sw = quad ^ (l16 & 3);

    const unsigned short* yhb = YH + (size_t)b * COUT * MODES;
    const float* bab = BA + (size_t)b * NX * MODES + (size_t)n0 * MODES;

    bool isA = (t < 512);
    int j  = t & 511;
    int rr = j >> 2, seg = j & 3;
    int ssw = (seg ^ (rr & 3)) << 3;

    const unsigned short* ga = yhb + (size_t)rr * MODES + seg * 8;
    const float* gb = bab + (size_t)rr * MODES + seg * 8;

    f32x4 acc[2][2];
#pragma unroll
    for (int i = 0; i < 2; i++)
#pragma unroll
        for (int jj = 0; jj < 2; jj++) acc[i][jj] = (f32x4){0.f, 0.f, 0.f, 0.f};

    bf16x8 sa; f32x4 sb0, sb1;
    if (isA) sa = *(const bf16x8*)ga;
    else { sb0 = *(const f32x4*)gb; sb1 = *(const f32x4*)(gb + 4); }

    for (int p = 0; p < 8; p++) {
        if (p) __syncthreads();
        if (isA) {
            *(bf16x8*)(As + rr * 40 + ssw) = sa;
        } else {
            bf16x8 v;
            v[0] = (short)f2bf(sb0[0]); v[1] = (short)f2bf(sb0[1]);
            v[2] = (short)f2bf(sb0[2]); v[3] = (short)f2bf(sb0[3]);
            v[4] = (short)f2bf(sb1[0]); v[5] = (short)f2bf(sb1[1]);
            v[6] = (short)f2bf(sb1[2]); v[7] = (short)f2bf(sb1[3]);
            *(bf16x8*)(Bs + rr * 40 + ssw) = v;
        }
        __syncthreads();

        if (p < 7) {
            if (isA) { ga += 32; sa = *(const bf16x8*)ga; }
            else     { gb += 32; sb0 = *(const f32x4*)gb; sb1 = *(const f32x4*)(gb + 4); }
        }

        bf16x8 af[2], bfv[2];
#pragma unroll
        for (int tm = 0; tm < 2; tm++)
            af[tm] = *(const bf16x8*)(As + (wm * 32 + tm * 16 + l16) * 40 + (sw << 3));
#pragma unroll
        for (int tn = 0; tn < 2; tn++)
            bfv[tn] = *(const bf16x8*)(Bs + (wn * 32 + tn * 16 + l16) * 40 + (sw << 3));
#pragma unroll
        for (int tm = 0; tm < 2; tm++)
#pragma unroll
            for (int tn = 0; tn < 2; tn++)
                acc[tm][tn] = __builtin_amdgcn_mfma_f32_16x16x32_bf16(af[tm], bfv[tn], acc[tm][tn], 0, 0, 0);
    }

    float* yb = Y + (size_t)b * COUT * NX;
#pragma unroll
    for (int tm = 0; tm < 2; tm++) {
        int o = wm * 32 + tm * 16 + quad * 4;
#pragma unroll
        for (int tn = 0; tn < 2; tn++) {
            int n = n0 + wn * 32 + tn * 16 + l16;
#pragma unroll
            for (int r = 0; r < 4; r++)
                yb[(size_t)(o + r) * NX + n] = acc[tm][tn][r];
        }
    }
}

extern "C" void kernel_launch(void* const* d_in, const int* in_sizes, int n_in,
                              void* d_out, int out_size, void* d_ws, size_t ws_size,
                              hipStream_t stream) {
    const float* X  = (const float*)d_in[0];  // [8][128][8192]
    const float* WB = (const float*)d_in[1];  // [8][8192][256]
    const float* BA = (const float*)d_in[2];  // [8][8192][256]
    const float* W  = (const float*)d_in[3];  // [128][128][32]
    const float* D  = (const float*)d_in[4];  // [32][256]
    float* Y = (float*)d_out;                 // [8][128][8192]

    char* ws = (char*)d_ws;
    unsigned short* Wk   = (unsigned short*)ws;                  // 8 MB bf16 [k][o][i]
    float*          XHT  = (float*)(ws + (8u << 20));            // 1 MB fp32 [k][b][i]
    unsigned short* YH   = (unsigned short*)(ws + (9u << 20));   // 0.5 MB bf16 [b][o][k]
    unsigned short* PART = (unsigned short*)(ws + (10u << 20));  // 8.4 MB bf16 [b][np][c][k]

    k1_wk  <<<dim3(256, 4),   256,  0, stream>>>(W, D, Wk);
    k2_xhat<<<dim3(16, 8, 2), 1024, 0, stream>>>(X, WB, PART);
    k2b_red<<<dim3(32, 2),    256,  0, stream>>>(PART, XHT);
    k3_yhat<<<dim3(256, 2),   256,  0, stream>>>(XHT, Wk, YH);
    k4_y   <<<dim3(64, 8),    1024, 0, stream>>>(YH, BA, Y);
}

// Round 5
// 220.365 us; speedup vs baseline: 1.0350x; 1.0350x over previous
//
#include <hip/hip_runtime.h>

#define B_    8
#define CIN   128
#define COUT  128
#define NX    8192
#define KMJ   32
#define MODES 256

typedef short bf16x8 __attribute__((ext_vector_type(8)));
typedef float f32x4  __attribute__((ext_vector_type(4)));

__device__ __forceinline__ float bf2f(unsigned short u) {
    union { unsigned int i; float f; } v; v.i = ((unsigned int)u) << 16; return v.f;
}
__device__ __forceinline__ unsigned short f2bf(float f) {
    union { float f; unsigned int i; } v; v.f = f;
    unsigned int x = v.i;
    return (unsigned short)((x + 0x7fffu + ((x >> 16) & 1u)) >> 16);
}
__device__ __forceinline__ bf16x8 cvt8(const float* __restrict__ p) {
    f32x4 a = *(const f32x4*)p;
    f32x4 b = *(const f32x4*)(p + 4);
    bf16x8 r;
    r[0] = (short)f2bf(a[0]); r[1] = (short)f2bf(a[1]);
    r[2] = (short)f2bf(a[2]); r[3] = (short)f2bf(a[3]);
    r[4] = (short)f2bf(b[0]); r[5] = (short)f2bf(b[1]);
    r[6] = (short)f2bf(b[2]); r[7] = (short)f2bf(b[3]);
    return r;
}
__device__ __forceinline__ ushort4 cvt4(f32x4 a) {
    ushort4 r;
    r.x = f2bf(a[0]); r.y = f2bf(a[1]); r.z = f2bf(a[2]); r.w = f2bf(a[3]);
    return r;
}

// ---------------------------------------------------------------------------
// K1 v3: Wk[k][o][i] = sum_j D[j][k] * weights[i][o][j]   (unchanged)
// ---------------------------------------------------------------------------
__global__ __launch_bounds__(256) void k1_wk(const float* __restrict__ W,
                                             const float* __restrict__ D,
                                             unsigned short* __restrict__ Wk) {
    int wave = threadIdx.x >> 6, lane = threadIdx.x & 63;
    int quad = lane >> 4, l16 = lane & 15;
    int gw  = blockIdx.x * 4 + wave;
    int oi0 = gw * 16;
    int i0  = oi0 & 127, o0 = oi0 >> 7;
    bf16x8 bfrag = cvt8(W + ((size_t)(i0 + l16) * COUT + o0) * KMJ + quad * 8);
#pragma unroll
    for (int m = 0; m < 4; m++) {
        int k0 = (blockIdx.y * 4 + m) * 16;
        bf16x8 afrag;
#pragma unroll
        for (int jj = 0; jj < 8; jj++)
            afrag[jj] = (short)f2bf(D[(quad * 8 + jj) * MODES + k0 + l16]);
        f32x4 acc = {0.f, 0.f, 0.f, 0.f};
        acc = __builtin_amdgcn_mfma_f32_16x16x32_bf16(afrag, bfrag, acc, 0, 0, 0);
#pragma unroll
        for (int r = 0; r < 4; r++)
            Wk[(size_t)(k0 + quad * 4 + r) * (CIN * COUT) + oi0 + l16] = f2bf(acc[r]);
    }
}

// ---------------------------------------------------------------------------
// K2 v8: PART[b][nt][c][k] = sum_{n in 256-chunk nt} x[b][c][n]*wb[b][n][k]
//
// Round-4 post-mortem: every kernel in this pipeline serves ~3 TB/s
// L2/L3-side regardless of occupancy/depth/barriers -> only LOGICAL BYTES
// matter. v8 merges the kh split: full k=256 per block. X read ONCE
// (-33.5MB logical); WB rows consumed whole (each lane loads 64B contiguous
// -> clean line utilization, vs 512B half-rows). PART back to 32x256-n
// chunks (bitwise-same XH as round 3). 8 passes (half the barrier-drains).
// Grid (32,8) = 256 blocks x 16 waves.
// ---------------------------------------------------------------------------
__global__ __launch_bounds__(1024, 4) void k2_xhat(const float* __restrict__ X,
                                                   const float* __restrict__ WB,
                                                   unsigned short* __restrict__ PART) {
    __shared__ __align__(16) unsigned short Xs[128 * 40];    // [c][32n], 80B rows
    __shared__ __align__(16) unsigned short WBT[256 * 40];   // [k][32n], 80B rows
    int nt = blockIdx.x, b = blockIdx.y;
    int r0 = nt * 256;
    int t  = threadIdx.x;
    int wave = t >> 6, lane = t & 63;
    int wm = wave >> 2, wk = wave & 3;     // 16 waves: 4m x 4k over 128c x 256k
    int quad = lane >> 4, l16 = lane & 15;
    int sw = quad ^ (l16 & 3);             // slot swizzle for frag reads

    const float* xb  = X  + (size_t)b * CIN * NX;
    const float* wbb = WB + (size_t)b * NX * MODES;

    bool isX = (t >= 512);                 // waves 8..15 stage X, 0..7 stage WB
    int j  = t & 511;
    int xr = j >> 2, xseg = j & 3;         // X: row xr, cols xseg*8..+7
    int kseg = j >> 4, np2 = j & 15;       // WB: k in [8kseg,8kseg+8), rows 2np2,2np2+1

    const float* gx = xb + (size_t)xr * NX + r0 + xseg * 8;
    const float* gw = wbb + (size_t)(r0 + 2 * np2) * MODES + 8 * kseg;
    unsigned short* xw = Xs + xr * 40 + ((xseg ^ (xr & 3)) << 3);

    f32x4 acc[2][4];
#pragma unroll
    for (int i = 0; i < 2; i++)
#pragma unroll
        for (int jj = 0; jj < 4; jj++) acc[i][jj] = (f32x4){0.f, 0.f, 0.f, 0.f};

    f32x4 st0, st1, st2, st3;
    if (isX) {
        st0 = *(const f32x4*)gx; st1 = *(const f32x4*)(gx + 4);
    } else {
        st0 = *(const f32x4*)gw;           st1 = *(const f32x4*)(gw + 4);
        st2 = *(const f32x4*)(gw + MODES); st3 = *(const f32x4*)(gw + MODES + 4);
    }

    for (int p = 0; p < 8; p++) {
        if (p) __syncthreads();            // prev pass frag reads complete
        if (isX) {
            *(ushort4*)xw       = cvt4(st0);
            *(ushort4*)(xw + 4) = cvt4(st1);
        } else {
            // transposed: for each of 8 k's, pack (n=2np2, 2np2+1) as one dword
#pragma unroll
            for (int jj = 0; jj < 8; jj++) {
                int k = 8 * kseg + jj;
                float v0 = (jj < 4) ? st0[jj] : st1[jj - 4];
                float v1 = (jj < 4) ? st2[jj] : st3[jj - 4];
                unsigned int w = (unsigned int)f2bf(v0) |
                                 ((unsigned int)f2bf(v1) << 16);
                *(unsigned int*)(WBT + k * 40 + (((np2 >> 2) ^ (k & 3)) << 3) + ((np2 & 3) << 1)) = w;
            }
        }
        __syncthreads();                   // staging visible

        if (p < 7) {                       // issue next pass; drains over MFMA
            if (isX) {
                gx += 32;
                st0 = *(const f32x4*)gx; st1 = *(const f32x4*)(gx + 4);
            } else {
                gw += (size_t)32 * MODES;
                st0 = *(const f32x4*)gw;           st1 = *(const f32x4*)(gw + 4);
                st2 = *(const f32x4*)(gw + MODES); st3 = *(const f32x4*)(gw + MODES + 4);
            }
        }

        bf16x8 af[2], bfv[4];
#pragma unroll
        for (int tm = 0; tm < 2; tm++)
            af[tm] = *(const bf16x8*)(Xs + (wm * 32 + tm * 16 + l16) * 40 + (sw << 3));
#pragma unroll
        for (int tn = 0; tn < 4; tn++)
            bfv[tn] = *(const bf16x8*)(WBT + (wk * 64 + tn * 16 + l16) * 40 + (sw << 3));
#pragma unroll
        for (int tm = 0; tm < 2; tm++)
#pragma unroll
            for (int tn = 0; tn < 4; tn++)
                acc[tm][tn] = __builtin_amdgcn_mfma_f32_16x16x32_bf16(af[tm], bfv[tn], acc[tm][tn], 0, 0, 0);
    }

    unsigned short* pb = PART + ((size_t)b * 32 + nt) * (CIN * MODES);
#pragma unroll
    for (int tm = 0; tm < 2; tm++) {
        int c = wm * 32 + tm * 16 + quad * 4;
#pragma unroll
        for (int tn = 0; tn < 4; tn++) {
            int km = wk * 64 + tn * 16 + l16;
#pragma unroll
            for (int r = 0; r < 4; r++)
                pb[(size_t)(c + r) * MODES + km] = f2bf(acc[tm][tn][r]);
        }
    }
}

// ---------------------------------------------------------------------------
// K2b v2 (round-3 form, reverted): XH[b][c][k] = sum_nt PART[b][nt][c][k]
// Coalesced scalar loads (consecutive threads -> consecutive k), 1024 blocks.
// Round-4's "transposing" v3 regressed ~10us (512B-stride 16B lane reads).
// ---------------------------------------------------------------------------
__global__ __launch_bounds__(256) void k2b_red(const unsigned short* __restrict__ PART,
                                               float* __restrict__ XH) {
    int e = blockIdx.x * 256 + threadIdx.x;            // 0..262143
    const unsigned short* p = PART + (size_t)(e >> 15) * 32 * (CIN * MODES) + (e & 32767);
    float acc = 0.f;
#pragma unroll
    for (int nt = 0; nt < 32; nt++) acc += bf2f(p[nt * (CIN * MODES)]);
    XH[e] = acc;
}

// ---------------------------------------------------------------------------
// K3 v3 (round-3 form, reverted): y_hat[b][o][k] = sum_i x_hat[b][i][k]*Wk[k][o][i]
// ---------------------------------------------------------------------------
__global__ __launch_bounds__(256, 2) void k3_yhat(const float* __restrict__ XH,
                                                  const unsigned short* __restrict__ Wk,
                                                  unsigned short* __restrict__ YH) {
    __shared__ float xs[128][8];
    int k = blockIdx.x, oh = blockIdx.y;
    int t = threadIdx.x;
#pragma unroll
    for (int l = 0; l < 4; l++) {
        int e = l * 256 + t;                   // 0..1023
        int i = e >> 3, bb = e & 7;
        xs[i][bb] = XH[(size_t)bb * (CIN * MODES) + (size_t)i * MODES + k];
    }
    int o = oh * 64 + (t & 63), bq = t >> 6;   // bq 0..3 -> b = 2bq, 2bq+1
    const unsigned short* wp = Wk + (size_t)k * (CIN * COUT) + (size_t)o * CIN;
    bf16x8 wc[16];
#pragma unroll
    for (int ii = 0; ii < 16; ii++)
        wc[ii] = *(const bf16x8*)(wp + ii * 8); // burst 16x16B
    __syncthreads();
    float a0 = 0.f, a1 = 0.f;
#pragma unroll
    for (int ii = 0; ii < 16; ii++)
#pragma unroll
        for (int jj = 0; jj < 8; jj++) {
            float w = bf2f((unsigned short)wc[ii][jj]);
            int i = ii * 8 + jj;
            a0 += w * xs[i][bq * 2];
            a1 += w * xs[i][bq * 2 + 1];
        }
    YH[((size_t)(bq * 2)     * COUT + o) * MODES + k] = f2bf(a0);
    YH[((size_t)(bq * 2 + 1) * COUT + o) * MODES + k] = f2bf(a1);
}

// ---------------------------------------------------------------------------
// K4 v4: y[b][c][n] = sum_k y_hat[b][c][k] * bases[b][n][k]   (unchanged)
// ---------------------------------------------------------------------------
__global__ __launch_bounds__(1024, 8) void k4_y(const unsigned short* __restrict__ YH,
                                                const float* __restrict__ BA,
                                                float* __restrict__ Y) {
    __shared__ __align__(16) unsigned short As[128 * 40];   // [c][32k]
    __shared__ __align__(16) unsigned short Bs[128 * 40];   // [n][32k]
    int b  = blockIdx.y;
    int n0 = blockIdx.x * 128;
    int t  = threadIdx.x;
    int wave = t >> 6, lane = t & 63;
    int wm = wave >> 2, wn = wave & 3;
    int quad = lane >> 4, l16 = lane & 15;
    int sw = quad ^ (l16 & 3);

    const unsigned short* yhb = YH + (size_t)b * COUT * MODES;
    const float* bab = BA + (size_t)b * NX * MODES + (size_t)n0 * MODES;

    bool isA = (t < 512);
    int j  = t & 511;
    int rr = j >> 2, seg = j & 3;
    int ssw = (seg ^ (rr & 3)) << 3;

    const unsigned short* ga = yhb + (size_t)rr * MODES + seg * 8;
    const float* gb = bab + (size_t)rr * MODES + seg * 8;

    f32x4 acc[2][2];
#pragma unroll
    for (int i = 0; i < 2; i++)
#pragma unroll
        for (int jj = 0; jj < 2; jj++) acc[i][jj] = (f32x4){0.f, 0.f, 0.f, 0.f};

    bf16x8 sa; f32x4 sb0, sb1;
    if (isA) sa = *(const bf16x8*)ga;
    else { sb0 = *(const f32x4*)gb; sb1 = *(const f32x4*)(gb + 4); }

    for (int p = 0; p < 8; p++) {
        if (p) __syncthreads();
        if (isA) {
            *(bf16x8*)(As + rr * 40 + ssw) = sa;
        } else {
            bf16x8 v;
            v[0] = (short)f2bf(sb0[0]); v[1] = (short)f2bf(sb0[1]);
            v[2] = (short)f2bf(sb0[2]); v[3] = (short)f2bf(sb0[3]);
            v[4] = (short)f2bf(sb1[0]); v[5] = (short)f2bf(sb1[1]);
            v[6] = (short)f2bf(sb1[2]); v[7] = (short)f2bf(sb1[3]);
            *(bf16x8*)(Bs + rr * 40 + ssw) = v;
        }
        __syncthreads();

        if (p < 7) {
            if (isA) { ga += 32; sa = *(const bf16x8*)ga; }
            else     { gb += 32; sb0 = *(const f32x4*)gb; sb1 = *(const f32x4*)(gb + 4); }
        }

        bf16x8 af[2], bfv[2];
#pragma unroll
        for (int tm = 0; tm < 2; tm++)
            af[tm] = *(const bf16x8*)(As + (wm * 32 + tm * 16 + l16) * 40 + (sw << 3));
#pragma unroll
        for (int tn = 0; tn < 2; tn++)
            bfv[tn] = *(const bf16x8*)(Bs + (wn * 32 + tn * 16 + l16) * 40 + (sw << 3));
#pragma unroll
        for (int tm = 0; tm < 2; tm++)
#pragma unroll
            for (int tn = 0; tn < 2; tn++)
                acc[tm][tn] = __builtin_amdgcn_mfma_f32_16x16x32_bf16(af[tm], bfv[tn], acc[tm][tn], 0, 0, 0);
    }

    float* yb = Y + (size_t)b * COUT * NX;
#pragma unroll
    for (int tm = 0; tm < 2; tm++) {
        int o = wm * 32 + tm * 16 + quad * 4;
#pragma unroll
        for (int tn = 0; tn < 2; tn++) {
            int n = n0 + wn * 32 + tn * 16 + l16;
#pragma unroll
            for (int r = 0; r < 4; r++)
                yb[(size_t)(o + r) * NX + n] = acc[tm][tn][r];
        }
    }
}

extern "C" void kernel_launch(void* const* d_in, const int* in_sizes, int n_in,
                              void* d_out, int out_size, void* d_ws, size_t ws_size,
                              hipStream_t stream) {
    const float* X  = (const float*)d_in[0];  // [8][128][8192]
    const float* WB = (const float*)d_in[1];  // [8][8192][256]
    const float* BA = (const float*)d_in[2];  // [8][8192][256]
    const float* W  = (const float*)d_in[3];  // [128][128][32]
    const float* D  = (const float*)d_in[4];  // [32][256]
    float* Y = (float*)d_out;                 // [8][128][8192]

    char* ws = (char*)d_ws;
    unsigned short* Wk   = (unsigned short*)ws;                  // 8 MB bf16 [k][o][i]
    float*          XH   = (float*)(ws + (8u << 20));            // 1 MB fp32 [b][c][k]
    unsigned short* YH   = (unsigned short*)(ws + (9u << 20));   // 0.5 MB bf16 [b][o][k]
    unsigned short* PART = (unsigned short*)(ws + (10u << 20));  // 16 MB bf16 [b][nt][c][k]

    k1_wk  <<<dim3(256, 4),   256,  0, stream>>>(W, D, Wk);
    k2_xhat<<<dim3(32, 8),    1024, 0, stream>>>(X, WB, PART);
    k2b_red<<<1024,           256,  0, stream>>>(PART, XH);
    k3_yhat<<<dim3(256, 2),   256,  0, stream>>>(XH, Wk, YH);
    k4_y   <<<dim3(64, 8),    1024, 0, stream>>>(YH, BA, Y);
}